// Round 15
// baseline (56.882 us; speedup 1.0000x reference)
//
#include <hip/hip_runtime.h>
#include <math.h>

#define NLEV 44
#define NDENSE 15          // levels 0..14 dense ((res+1)^2 <= 1024)
#define NHASH (NLEV - NDENSE)
#define IMG 178
#define NPTS (IMG*IMG)
#define HASH_SIZE 1024
#define PRIME 2654435761u
#define BLOCK 1024
#define HBASE2 18432u       // byte offset of first hashed bf16 table (2048-aligned, >= 8888*2)

typedef __attribute__((ext_vector_type(2))) float f32x2;

// Hardcoded RES table (verified on host vs llrint; mismatch -> SOFT fallback kernel)
constexpr int RES_C[NLEV] = {16,17,18,18,19,20,21,22,24,25,26,27,29,30,31,
                             33,35,36,38,40,42,44,46,49,51,54,56,59,62,65,
                             68,72,75,79,83,87,91,96,101,105,111,116,122,128};
constexpr int size_c(int l) { int r = RES_C[l]; int s = (r+1)*(r+1); return s <= 1024 ? s : 1024; }
constexpr int off_c(int l)  { int o = 0; for (int i = 0; i < l; ++i) o += size_c(i); return o; }

struct LevelParams {
    int res[NLEV];
    int offs[NLEV];
    int total;
};

// packed fma: acc += a(pair) * b(sgpr pair)
#define PKFMA_S(acc, a, b) \
    asm("v_pk_fma_f32 %0, %1, %2, %0" : "+v"(acc) : "v"(a), "s"(b))

#define FRACT(dst, src) asm("v_fract_f32 %0, %1" : "=v"(dst) : "v"(src))

__device__ __forceinline__ float bf16_at(const char* lds, unsigned a) {
    const unsigned short u = *(const unsigned short*)(lds + a);   // ds_read_u16
    return __uint_as_float(((unsigned)u) << 16);                  // 1 VALU
}
__device__ __forceinline__ unsigned bf16r(float f) {              // round-to-nearest-even
    const unsigned u = __float_as_uint(f);
    return (u + 0x7FFFu + ((u >> 16) & 1u)) >> 16;
}
__device__ __forceinline__ unsigned pack2bf(float a, float b) {
    return bf16r(a) | (bf16r(b) << 16);
}

// ---- pre-kernel: transpose W1 [b][o][l] -> [b][l][o] into d_ws ----
__global__ __launch_bounds__(1024) void transpose_w1(const float* __restrict__ w1,
                                                     float* __restrict__ w1t) {
    const int b = blockIdx.x;
    const int i = threadIdx.x;
    if (i < 16 * NLEV) {
        const int l = i >> 4, o = i & 15;
        w1t[(size_t)b * 16 * NLEV + i] = w1[(size_t)b * 16 * NLEV + o * NLEV + l];
    }
}

// ================= HARD kernel (compile-time level constants, bf16 LDS tables) ===========

template<int L>
__device__ __forceinline__ float dense_feat(const char* lds, float2 xy) {
    constexpr float rf = (float)RES_C[L];
    constexpr int st = RES_C[L] + 1;
    constexpr unsigned off2 = (unsigned)(off_c(L) * 2);
    const float sx = xy.x * rf, sy = xy.y * rf;
    const int ix0 = (int)sx, iy0 = (int)sy;    // x in [0,1): trunc==floor, no clamp needed
    float fx, fy;
    FRACT(fx, sx);
    FRACT(fy, sy);
    const unsigned aD = off2 + (((unsigned)(iy0 * st + ix0)) << 1);
    const float v00 = bf16_at(lds, aD);
    const float v10 = bf16_at(lds, aD + 2);
    const float v01 = bf16_at(lds, aD + 2 * st);
    const float v11 = bf16_at(lds, aD + 2 * st + 2);
    const float vx0 = fmaf(fx, v10 - v00, v00);
    const float vx1 = fmaf(fx, v11 - v01, v01);
    return fmaf(fy, vx1 - vx0, vx0);
}

// bf16 hashed tables, byte-space XOR addressing:
//   entry byte = (px*2) ^ ((py*433 & 1023)*2); table base 2048-aligned
template<int L>
__device__ __forceinline__ float hash_feat(const char* lds, float2 xy) {
    constexpr float rf = (float)RES_C[L];
    constexpr unsigned lbase = HBASE2 + (unsigned)(L - NDENSE) * 2048u;
    const float sx = xy.x * rf, sy = xy.y * rf;
    const int ix0 = (int)sx, iy0 = (int)sy;
    float fx, fy;
    FRACT(fx, sx);
    FRACT(fy, sy);
    const unsigned pyb0 = ((unsigned)iy0 * 866u) & 2046u;   // (py*PRIME&1023)*2
    const unsigned pyb1 = (pyb0 + 866u) & 2046u;
    const unsigned bx0 = ((unsigned)ix0) << 1;
    const unsigned bx1 = bx0 + 2u;
    const float v00 = bf16_at(lds, lbase + (bx0 ^ pyb0));
    const float v01 = bf16_at(lds, lbase + (bx0 ^ pyb1));
    const float v10 = bf16_at(lds, lbase + (bx1 ^ pyb0));
    const float v11 = bf16_at(lds, lbase + (bx1 ^ pyb1));
    const float vx0 = fmaf(fx, v10 - v00, v00);
    const float vx1 = fmaf(fx, v11 - v01, v01);
    return fmaf(fy, vx1 - vx0, vx0);
}

template<int L>
__device__ __forceinline__ void levels_from(const char* lds, const float* __restrict__ w1b,
                                            const float2& xy, f32x2* __restrict__ h1) {
    if constexpr (L < NLEV) {
        float f;
        if constexpr (L < NDENSE) f = dense_feat<L>(lds, xy);
        else                      f = hash_feat<L>(lds, xy);
        const f32x2* wp = (const f32x2*)(w1b + L * 16);   // uniform -> s_load
        f32x2 wlv[8];
#pragma unroll
        for (int j = 0; j < 8; ++j) wlv[j] = wp[j];
        f32x2 fv; fv.x = f; fv.y = f;
#pragma unroll
        for (int j = 0; j < 8; ++j) PKFMA_S(h1[j], fv, wlv[j]);
        levels_from<L + 1>(lds, w1b, xy, h1);
    }
}

__device__ __forceinline__ void mlp_store(const float* __restrict__ w2b,
                                          const float* __restrict__ w3b,
                                          float* __restrict__ out, size_t bofs,
                                          f32x2* __restrict__ h1, int n) {
#pragma unroll
    for (int j = 0; j < 8; ++j) {
        h1[j].x = fmaxf(h1[j].x, 0.f);
        h1[j].y = fmaxf(h1[j].y, 0.f);
    }
    float h2[16];
#pragma unroll
    for (int o = 0; o < 16; ++o) {
        const f32x2* w2v = (const f32x2*)(w2b + o * 16);
        f32x2 acc; acc.x = 0.f; acc.y = 0.f;
#pragma unroll
        for (int k = 0; k < 8; ++k) PKFMA_S(acc, h1[k], w2v[k]);
        h2[o] = fmaxf(acc.x + acc.y, 0.f);
    }
    f32x2 h2v[8];
#pragma unroll
    for (int j = 0; j < 8; ++j) { h2v[j].x = h2[2 * j]; h2v[j].y = h2[2 * j + 1]; }
    float rgb[3];
#pragma unroll
    for (int c = 0; c < 3; ++c) {
        const f32x2* w3v = (const f32x2*)(w3b + c * 16);
        f32x2 acc; acc.x = 0.f; acc.y = 0.f;
#pragma unroll
        for (int k = 0; k < 8; ++k) PKFMA_S(acc, h2v[k], w3v[k]);
        const float z = acc.x + acc.y;
        const float e = __builtin_amdgcn_exp2f(z * -1.44269504088896f);
        rgb[c] = __builtin_amdgcn_rcpf(1.f + e);
    }
    ((float3*)out)[bofs + n] = make_float3(rgb[0], rgb[1], rgb[2]);
}

__global__ __launch_bounds__(BLOCK) void shacira_hard(
    const float* __restrict__ x, const float* __restrict__ codebook,
    const float* __restrict__ w1t, const float* __restrict__ w2,
    const float* __restrict__ w3, float* __restrict__ out)
{
    extern __shared__ char lds[];
    const int tid = threadIdx.x;
    const int b = blockIdx.y;
    constexpr int TOTAL = off_c(NLEV - 1) + size_c(NLEV - 1);   // 38584
    constexpr int DENSE_TOT = off_c(NDENSE);                    // 8888
    const float* cbg = codebook + (size_t)b * TOTAL;

    // stage fp32 -> bf16: dense at [0, 17776); hashed at HBASE2 + (l-15)*2048
    {
        const float2* s2 = (const float2*)cbg;
        unsigned* d32 = (unsigned*)lds;
        for (int i = tid; i < DENSE_TOT / 2; i += BLOCK) {
            const float2 v = s2[i];
            d32[i] = pack2bf(v.x, v.y);
        }
        const float2* h2s = (const float2*)(cbg + DENSE_TOT);
        unsigned* h32 = (unsigned*)(lds + HBASE2);
        for (int i = tid; i < (NHASH * HASH_SIZE) / 2; i += BLOCK) {
            const float2 v = h2s[i];
            h32[i] = pack2bf(v.x, v.y);
        }
    }
    __syncthreads();

    const int n = blockIdx.x * BLOCK + tid;
    if (n >= NPTS) return;

    const float* w1b = w1t + (size_t)b * 16 * NLEV;
    const float* w2b = w2 + (size_t)b * 256;
    const float* w3b = w3 + (size_t)b * 48;

    const float2 xy = ((const float2*)x)[(size_t)b * NPTS + n];

    f32x2 h1[8];
#pragma unroll
    for (int j = 0; j < 8; ++j) { h1[j].x = 0.f; h1[j].y = 0.f; }

    levels_from<0>(lds, w1b, xy, h1);

    mlp_store(w2b, w3b, out, (size_t)b * NPTS, h1, n);
}

// ================= SOFT fallback kernel (R7, runtime level table, fp32) =================

template<bool TP>
__global__ __launch_bounds__(BLOCK) void shacira_soft(
    const float* __restrict__ x, const float* __restrict__ codebook,
    const float* __restrict__ w1, const float* __restrict__ w1t,
    const float* __restrict__ w2, const float* __restrict__ w3,
    float* __restrict__ out, LevelParams lp)
{
    extern __shared__ float sCB[];
    const int total = lp.total;
    const int tid = threadIdx.x;
    const int b = blockIdx.y;
    {
        const float* cbg = codebook + (size_t)b * total;
        const float4* src = (const float4*)cbg;
        float4* dst = (float4*)sCB;
        const int n4 = total >> 2;
        for (int i = tid; i < n4; i += BLOCK) dst[i] = src[i];
        for (int i = (n4 << 2) + tid; i < total; i += BLOCK) sCB[i] = cbg[i];
    }
    __syncthreads();

    const float* w1b = TP ? (w1t + (size_t)b * 16 * NLEV) : (w1 + (size_t)b * 16 * NLEV);
    const float* w2b = w2 + (size_t)b * 256;
    const float* w3b = w3 + (size_t)b * 48;

    const int n = blockIdx.x * BLOCK + tid;
    if (n >= NPTS) return;
    const float2 xy = ((const float2*)x)[(size_t)b * NPTS + n];

    f32x2 h1[8];
#pragma unroll
    for (int j = 0; j < 8; ++j) { h1[j].x = 0.f; h1[j].y = 0.f; }

#pragma unroll
    for (int l = 0; l < NDENSE; ++l) {
        const int res = lp.res[l];
        const int st  = res + 1;
        const int off = lp.offs[l];
        const float rf = (float)res;
        f32x2 wlv[8];
        if constexpr (TP) {
            const f32x2* wp = (const f32x2*)(w1b + l * 16);
#pragma unroll
            for (int j = 0; j < 8; ++j) wlv[j] = wp[j];
        } else {
#pragma unroll
            for (int j = 0; j < 8; ++j) {
                wlv[j].x = w1b[(2 * j) * NLEV + l];
                wlv[j].y = w1b[(2 * j + 1) * NLEV + l];
            }
        }
        const float sx = xy.x * rf, sy = xy.y * rf;
        const int ix0 = (int)sx, iy0 = (int)sy;
        const float fx = sx - (float)ix0, fy = sy - (float)iy0;
        const int r0 = off + iy0 * st + ix0;
        const float v00 = sCB[r0],      v10 = sCB[r0 + 1];
        const float v01 = sCB[r0 + st], v11 = sCB[r0 + st + 1];
        const float vx0 = fmaf(fx, v10 - v00, v00);
        const float vx1 = fmaf(fx, v11 - v01, v01);
        const float feat = fmaf(fy, vx1 - vx0, vx0);
        f32x2 f2; f2.x = feat; f2.y = feat;
#pragma unroll
        for (int j = 0; j < 8; ++j) PKFMA_S(h1[j], f2, wlv[j]);
    }

#pragma unroll
    for (int l = NDENSE; l < NLEV; ++l) {
        const int res = lp.res[l];
        const int off = lp.offs[l];
        const float rf = (float)res;
        f32x2 wlv[8];
        if constexpr (TP) {
            const f32x2* wp = (const f32x2*)(w1b + l * 16);
#pragma unroll
            for (int j = 0; j < 8; ++j) wlv[j] = wp[j];
        } else {
#pragma unroll
            for (int j = 0; j < 8; ++j) {
                wlv[j].x = w1b[(2 * j) * NLEV + l];
                wlv[j].y = w1b[(2 * j + 1) * NLEV + l];
            }
        }
        const float sx = xy.x * rf, sy = xy.y * rf;
        const int ix0 = (int)sx, iy0 = (int)sy;
        const float fx = sx - (float)ix0, fy = sy - (float)iy0;
        const unsigned px0 = (unsigned)ix0, px1 = px0 + 1u;
        const unsigned py0 = (unsigned)iy0 * PRIME, py1 = py0 + PRIME;
        const int i00 = (int)((px0 ^ py0) & (HASH_SIZE - 1));
        const int i01 = (int)((px0 ^ py1) & (HASH_SIZE - 1));
        const int i10 = (int)((px1 ^ py0) & (HASH_SIZE - 1));
        const int i11 = (int)((px1 ^ py1) & (HASH_SIZE - 1));
        const float v00 = sCB[off + i00];
        const float v01 = sCB[off + i01];
        const float v10 = sCB[off + i10];
        const float v11 = sCB[off + i11];
        const float vx0 = fmaf(fx, v10 - v00, v00);
        const float vx1 = fmaf(fx, v11 - v01, v01);
        const float feat = fmaf(fy, vx1 - vx0, vx0);
        f32x2 f2; f2.x = feat; f2.y = feat;
#pragma unroll
        for (int j = 0; j < 8; ++j) PKFMA_S(h1[j], f2, wlv[j]);
    }

#pragma unroll
    for (int j = 0; j < 8; ++j) {
        h1[j].x = fmaxf(h1[j].x, 0.f);
        h1[j].y = fmaxf(h1[j].y, 0.f);
    }
    float h2[16];
#pragma unroll
    for (int o = 0; o < 16; ++o) {
        const f32x2* w2v = (const f32x2*)(w2b + o * 16);
        f32x2 acc; acc.x = 0.f; acc.y = 0.f;
#pragma unroll
        for (int k = 0; k < 8; ++k) PKFMA_S(acc, h1[k], w2v[k]);
        h2[o] = fmaxf(acc.x + acc.y, 0.f);
    }
    f32x2 h2v[8];
#pragma unroll
    for (int j = 0; j < 8; ++j) { h2v[j].x = h2[2 * j]; h2v[j].y = h2[2 * j + 1]; }
    float rgb[3];
#pragma unroll
    for (int c = 0; c < 3; ++c) {
        const f32x2* w3v = (const f32x2*)(w3b + c * 16);
        f32x2 acc; acc.x = 0.f; acc.y = 0.f;
#pragma unroll
        for (int k = 0; k < 8; ++k) PKFMA_S(acc, h2v[k], w3v[k]);
        rgb[c] = 1.f / (1.f + expf(-(acc.x + acc.y)));
    }
    float* op = out + ((size_t)b * NPTS + n) * 3;
    op[0] = rgb[0]; op[1] = rgb[1]; op[2] = rgb[2];
}

extern "C" void kernel_launch(void* const* d_in, const int* in_sizes, int n_in,
                              void* d_out, int out_size, void* d_ws, size_t ws_size,
                              hipStream_t stream) {
    const float* x        = (const float*)d_in[0];
    const float* codebook = (const float*)d_in[1];
    const float* w1       = (const float*)d_in[2];
    const float* w2       = (const float*)d_in[3];
    const float* w3       = (const float*)d_in[4];
    float* out = (float*)d_out;

    const int B = in_sizes[0] / (NPTS * 2);

    // host-side ground truth table + hardcode verification
    LevelParams lp;
    bool hard_ok = true;
    int off = 0;
    for (int l = 0; l < NLEV; ++l) {
        const double r = 16.0 * pow(128.0 / 16.0, (double)l / (double)(NLEV - 1));
        const int res = (int)llrint(r);
        if (res != RES_C[l]) hard_ok = false;
        lp.res[l] = res;
        lp.offs[l] = off;
        const int sz = ((long long)(res + 1) * (res + 1) <= HASH_SIZE)
                           ? (res + 1) * (res + 1) : HASH_SIZE;
        off += sz;
    }
    lp.total = off;
    if (off != off_c(NLEV - 1) + size_c(NLEV - 1)) hard_ok = false;

    const size_t w1tBytes = (size_t)B * 16 * NLEV * 4;
    const bool tp = ws_size >= w1tBytes;

    dim3 grid1((NPTS + BLOCK - 1) / BLOCK, B);   // 1 point/thread (31 x B)

    if (hard_ok && tp) {
        transpose_w1<<<dim3(B), dim3(1024), 0, stream>>>(w1, (float*)d_ws);
        const size_t smemBytes = HBASE2 + (size_t)NHASH * 2048;   // 77824 -> 2 blocks/CU
        (void)hipFuncSetAttribute((const void*)shacira_hard,
                                  hipFuncAttributeMaxDynamicSharedMemorySize, (int)smemBytes);
        shacira_hard<<<grid1, dim3(BLOCK), smemBytes, stream>>>(
            x, codebook, (const float*)d_ws, w2, w3, out);
    } else if (tp) {
        transpose_w1<<<dim3(B), dim3(1024), 0, stream>>>(w1, (float*)d_ws);
        const size_t smemBytes = (size_t)lp.total * 4;
        (void)hipFuncSetAttribute((const void*)shacira_soft<true>,
                                  hipFuncAttributeMaxDynamicSharedMemorySize, (int)smemBytes);
        shacira_soft<true><<<grid1, dim3(BLOCK), smemBytes, stream>>>(
            x, codebook, w1, (const float*)d_ws, w2, w3, out, lp);
    } else {
        const size_t smemBytes = (size_t)lp.total * 4;
        (void)hipFuncSetAttribute((const void*)shacira_soft<false>,
                                  hipFuncAttributeMaxDynamicSharedMemorySize, (int)smemBytes);
        shacira_soft<false><<<grid1, dim3(BLOCK), smemBytes, stream>>>(
            x, codebook, w1, (const float*)0, w2, w3, out, lp);
    }
}

// Round 16
// 37.019 us; speedup vs baseline: 1.5366x; 1.5366x over previous
//
#include <hip/hip_runtime.h>
#include <math.h>

#define NLEV 44
#define NDENSE 15          // levels 0..14 dense ((res+1)^2 <= 1024)
#define NHASH (NLEV - NDENSE)
#define IMG 178
#define NPTS (IMG*IMG)
#define HASH_SIZE 1024
#define PRIME 2654435761u
#define BLOCK 1024
#define PTS_PER_BLOCK (2*BLOCK)
#define HBASE 36864u        // byte offset of first hashed table in LDS (4096-aligned, >= 8888*4)
#define PRIME_LOW_B 1732u   // (PRIME & 1023) << 2
#define PYMASK 4092u

typedef __attribute__((ext_vector_type(2))) float f32x2;

// Hardcoded RES table (verified on host vs llrint; mismatch -> SOFT fallback kernel)
constexpr int RES_C[NLEV] = {16,17,18,18,19,20,21,22,24,25,26,27,29,30,31,
                             33,35,36,38,40,42,44,46,49,51,54,56,59,62,65,
                             68,72,75,79,83,87,91,96,101,105,111,116,122,128};
constexpr int size_c(int l) { int r = RES_C[l]; int s = (r+1)*(r+1); return s <= 1024 ? s : 1024; }
constexpr int off_c(int l)  { int o = 0; for (int i = 0; i < l; ++i) o += size_c(i); return o; }

struct LevelParams {
    int res[NLEV];
    int offs[NLEV];
    int total;
};

// packed fma: acc += a(pair) * b(sgpr pair)
#define PKFMA_S(acc, a, b) \
    asm("v_pk_fma_f32 %0, %1, %2, %0" : "+v"(acc) : "v"(a), "s"(b))

#define FRACT(dst, src) asm("v_fract_f32 %0, %1" : "=v"(dst) : "v"(src))

// ---- pre-kernel: transpose W1 [b][o][l] -> [b][l][o] into d_ws ----
__global__ __launch_bounds__(1024) void transpose_w1(const float* __restrict__ w1,
                                                     float* __restrict__ w1t) {
    const int b = blockIdx.x;
    const int i = threadIdx.x;
    if (i < 16 * NLEV) {
        const int l = i >> 4, o = i & 15;
        w1t[(size_t)b * 16 * NLEV + i] = w1[(size_t)b * 16 * NLEV + o * NLEV + l];
    }
}

// ================= HARD kernel (compile-time level constants) =================

template<int L>
__device__ __forceinline__ float dense_feat(const char* lds, float2 xy) {
    constexpr float rf = (float)RES_C[L];
    constexpr int st = RES_C[L] + 1;
    constexpr unsigned off4 = (unsigned)(off_c(L) * 4);
    const float sx = xy.x * rf, sy = xy.y * rf;
    const int ix0 = (int)sx, iy0 = (int)sy;    // x in [0,1): trunc==floor, no clamp needed
    float fx, fy;
    FRACT(fx, sx);
    FRACT(fy, sy);
    const unsigned aD = off4 + (((unsigned)(iy0 * st + ix0)) << 2);
    const float v00 = *(const float*)(lds + aD);
    const float v10 = *(const float*)(lds + aD + 4);
    const float v01 = *(const float*)(lds + aD + 4 * st);
    const float v11 = *(const float*)(lds + aD + 4 * st + 4);
    const float vx0 = fmaf(fx, v10 - v00, v00);
    const float vx1 = fmaf(fx, v11 - v01, v01);
    return fmaf(fy, vx1 - vx0, vx0);
}

template<int L>
__device__ __forceinline__ float hash_feat(const char* lds, float2 xy) {
    constexpr float rf = (float)RES_C[L];
    constexpr unsigned lbase = HBASE + (unsigned)(L - NDENSE) * 4096u;  // 4096-aligned
    const float sx = xy.x * rf, sy = xy.y * rf;
    const int ix0 = (int)sx, iy0 = (int)sy;
    float fx, fy;
    FRACT(fx, sx);
    FRACT(fy, sy);
    // byte-space hash: addr = (lbase + px*4) ^ ((py*PRIME & 1023)*4)
    const unsigned pyb0 = ((unsigned)iy0 * PRIME_LOW_B) & PYMASK;
    const unsigned pyb1 = (pyb0 + PRIME_LOW_B) & PYMASK;
    const unsigned bpx0 = lbase + (((unsigned)ix0) << 2);
    const unsigned bpx1 = bpx0 + 4u;
    const float v00 = *(const float*)(lds + (bpx0 ^ pyb0));
    const float v01 = *(const float*)(lds + (bpx0 ^ pyb1));
    const float v10 = *(const float*)(lds + (bpx1 ^ pyb0));
    const float v11 = *(const float*)(lds + (bpx1 ^ pyb1));
    const float vx0 = fmaf(fx, v10 - v00, v00);
    const float vx1 = fmaf(fx, v11 - v01, v01);
    return fmaf(fy, vx1 - vx0, vx0);
}

template<int L>
__device__ __forceinline__ void level_apply(const float* __restrict__ w1b,
                                            float f0, float f1,
                                            f32x2* __restrict__ h1a, f32x2* __restrict__ h1b) {
    const f32x2* wp = (const f32x2*)(w1b + L * 16);   // uniform -> s_load
    f32x2 wlv[8];
#pragma unroll
    for (int j = 0; j < 8; ++j) wlv[j] = wp[j];
    f32x2 f0v; f0v.x = f0; f0v.y = f0;
    f32x2 f1v; f1v.x = f1; f1v.y = f1;
#pragma unroll
    for (int j = 0; j < 8; ++j) {
        PKFMA_S(h1a[j], f0v, wlv[j]);
        PKFMA_S(h1b[j], f1v, wlv[j]);
    }
}

template<int L>
__device__ __forceinline__ void levels_from(const char* lds, const float* __restrict__ w1b,
                                            const float2& xy0, const float2& xy1,
                                            f32x2* __restrict__ h1a, f32x2* __restrict__ h1b) {
    if constexpr (L < NLEV) {
        float f0, f1;
        if constexpr (L < NDENSE) {
            f0 = dense_feat<L>(lds, xy0);
            f1 = dense_feat<L>(lds, xy1);
        } else {
            f0 = hash_feat<L>(lds, xy0);
            f1 = hash_feat<L>(lds, xy1);
        }
        level_apply<L>(w1b, f0, f1, h1a, h1b);
        levels_from<L + 1>(lds, w1b, xy0, xy1, h1a, h1b);
    }
}

__device__ __forceinline__ void mlp_store(const float* __restrict__ w2b,
                                          const float* __restrict__ w3b,
                                          float* __restrict__ out, size_t bofs,
                                          f32x2* __restrict__ h1, int n, bool valid) {
    if (!valid) return;
#pragma unroll
    for (int j = 0; j < 8; ++j) {
        h1[j].x = fmaxf(h1[j].x, 0.f);
        h1[j].y = fmaxf(h1[j].y, 0.f);
    }
    float h2[16];
#pragma unroll
    for (int o = 0; o < 16; ++o) {
        const f32x2* w2v = (const f32x2*)(w2b + o * 16);
        f32x2 acc; acc.x = 0.f; acc.y = 0.f;
#pragma unroll
        for (int k = 0; k < 8; ++k) PKFMA_S(acc, h1[k], w2v[k]);
        h2[o] = fmaxf(acc.x + acc.y, 0.f);
    }
    f32x2 h2v[8];
#pragma unroll
    for (int j = 0; j < 8; ++j) { h2v[j].x = h2[2 * j]; h2v[j].y = h2[2 * j + 1]; }
    float rgb[3];
#pragma unroll
    for (int c = 0; c < 3; ++c) {
        const f32x2* w3v = (const f32x2*)(w3b + c * 16);
        f32x2 acc; acc.x = 0.f; acc.y = 0.f;
#pragma unroll
        for (int k = 0; k < 8; ++k) PKFMA_S(acc, h2v[k], w3v[k]);
        const float z = acc.x + acc.y;
        const float e = __builtin_amdgcn_exp2f(z * -1.44269504088896f);
        rgb[c] = __builtin_amdgcn_rcpf(1.f + e);
    }
    ((float3*)out)[bofs + n] = make_float3(rgb[0], rgb[1], rgb[2]);
}

__global__ __launch_bounds__(BLOCK) void shacira_hard(
    const float* __restrict__ x, const float* __restrict__ codebook,
    const float* __restrict__ w1t, const float* __restrict__ w2,
    const float* __restrict__ w3, float* __restrict__ out)
{
    extern __shared__ char lds[];
    const int tid = threadIdx.x;
    const int b = blockIdx.y;
    constexpr int TOTAL = off_c(NLEV - 1) + size_c(NLEV - 1);   // 38584
    constexpr int DENSE_TOT = off_c(NDENSE);                    // 8888
    const float* cbg = codebook + (size_t)b * TOTAL;

    // stage: dense fp32 at [0, 35552); hashed tables at HBASE + (l-15)*4096
    {
        const float4* srcD = (const float4*)cbg;
        float4* dstD = (float4*)lds;
        for (int i = tid; i < DENSE_TOT / 4; i += BLOCK) dstD[i] = srcD[i];
        const float4* srcH = (const float4*)(cbg + DENSE_TOT);
        float4* dstH = (float4*)(lds + HBASE);
        for (int i = tid; i < (NHASH * HASH_SIZE) / 4; i += BLOCK) dstH[i] = srcH[i];
    }
    __syncthreads();

    const float* w1b = w1t + (size_t)b * 16 * NLEV;
    const float* w2b = w2 + (size_t)b * 256;
    const float* w3b = w3 + (size_t)b * 48;

    const int n0 = blockIdx.x * PTS_PER_BLOCK + tid;
    const int n1 = n0 + BLOCK;
    const bool valid0 = n0 < NPTS;
    const bool valid1 = n1 < NPTS;
    const float2* xg = (const float2*)x + (size_t)b * NPTS;
    float2 xy0 = valid0 ? xg[n0] : make_float2(0.f, 0.f);
    float2 xy1 = valid1 ? xg[n1] : make_float2(0.f, 0.f);

    f32x2 h1a[8], h1b[8];
#pragma unroll
    for (int j = 0; j < 8; ++j) {
        h1a[j].x = 0.f; h1a[j].y = 0.f;
        h1b[j].x = 0.f; h1b[j].y = 0.f;
    }

    levels_from<0>(lds, w1b, xy0, xy1, h1a, h1b);

    const size_t bofs = (size_t)b * NPTS;
    mlp_store(w2b, w3b, out, bofs, h1a, n0, valid0);
    mlp_store(w2b, w3b, out, bofs, h1b, n1, valid1);
}

// ================= SOFT fallback kernel (R7, runtime level table) =================

template<bool TP>
__global__ __launch_bounds__(BLOCK) void shacira_soft(
    const float* __restrict__ x, const float* __restrict__ codebook,
    const float* __restrict__ w1, const float* __restrict__ w1t,
    const float* __restrict__ w2, const float* __restrict__ w3,
    float* __restrict__ out, LevelParams lp)
{
    extern __shared__ float sCB[];
    const int total = lp.total;
    const int tid = threadIdx.x;
    const int b = blockIdx.y;
    {
        const float* cbg = codebook + (size_t)b * total;
        const float4* src = (const float4*)cbg;
        float4* dst = (float4*)sCB;
        const int n4 = total >> 2;
        for (int i = tid; i < n4; i += BLOCK) dst[i] = src[i];
        for (int i = (n4 << 2) + tid; i < total; i += BLOCK) sCB[i] = cbg[i];
    }
    __syncthreads();

    const float* w1b = TP ? (w1t + (size_t)b * 16 * NLEV) : (w1 + (size_t)b * 16 * NLEV);
    const float* w2b = w2 + (size_t)b * 256;
    const float* w3b = w3 + (size_t)b * 48;

    const int n0 = blockIdx.x * PTS_PER_BLOCK + tid;
    const int n1 = n0 + BLOCK;
    const bool valid0 = n0 < NPTS;
    const bool valid1 = n1 < NPTS;
    const float2* xg = (const float2*)x + (size_t)b * NPTS;
    float2 xy0 = valid0 ? xg[n0] : make_float2(0.f, 0.f);
    float2 xy1 = valid1 ? xg[n1] : make_float2(0.f, 0.f);

    f32x2 h1a[8], h1b[8];
#pragma unroll
    for (int j = 0; j < 8; ++j) {
        h1a[j].x = 0.f; h1a[j].y = 0.f;
        h1b[j].x = 0.f; h1b[j].y = 0.f;
    }

#pragma unroll
    for (int l = 0; l < NDENSE; ++l) {
        const int res = lp.res[l];
        const int st  = res + 1;
        const int off = lp.offs[l];
        const float rf = (float)res;
        f32x2 wlv[8];
        if constexpr (TP) {
            const f32x2* wp = (const f32x2*)(w1b + l * 16);
#pragma unroll
            for (int j = 0; j < 8; ++j) wlv[j] = wp[j];
        } else {
#pragma unroll
            for (int j = 0; j < 8; ++j) {
                wlv[j].x = w1b[(2 * j) * NLEV + l];
                wlv[j].y = w1b[(2 * j + 1) * NLEV + l];
            }
        }
        auto dolevel = [&](const float2 xy, f32x2* h1) {
            const float sx = xy.x * rf, sy = xy.y * rf;
            const int ix0 = (int)sx, iy0 = (int)sy;
            const float fx = sx - (float)ix0, fy = sy - (float)iy0;
            const int r0 = off + iy0 * st + ix0;
            const float v00 = sCB[r0],      v10 = sCB[r0 + 1];
            const float v01 = sCB[r0 + st], v11 = sCB[r0 + st + 1];
            const float vx0 = fmaf(fx, v10 - v00, v00);
            const float vx1 = fmaf(fx, v11 - v01, v01);
            const float feat = fmaf(fy, vx1 - vx0, vx0);
            f32x2 f2; f2.x = feat; f2.y = feat;
#pragma unroll
            for (int j = 0; j < 8; ++j) PKFMA_S(h1[j], f2, wlv[j]);
        };
        dolevel(xy0, h1a);
        dolevel(xy1, h1b);
    }

#pragma unroll
    for (int l = NDENSE; l < NLEV; ++l) {
        const int res = lp.res[l];
        const int off = lp.offs[l];
        const float rf = (float)res;
        f32x2 wlv[8];
        if constexpr (TP) {
            const f32x2* wp = (const f32x2*)(w1b + l * 16);
#pragma unroll
            for (int j = 0; j < 8; ++j) wlv[j] = wp[j];
        } else {
#pragma unroll
            for (int j = 0; j < 8; ++j) {
                wlv[j].x = w1b[(2 * j) * NLEV + l];
                wlv[j].y = w1b[(2 * j + 1) * NLEV + l];
            }
        }
        auto dolevel = [&](const float2 xy, f32x2* h1) {
            const float sx = xy.x * rf, sy = xy.y * rf;
            const int ix0 = (int)sx, iy0 = (int)sy;
            const float fx = sx - (float)ix0, fy = sy - (float)iy0;
            const unsigned px0 = (unsigned)ix0, px1 = px0 + 1u;
            const unsigned py0 = (unsigned)iy0 * PRIME, py1 = py0 + PRIME;
            const int i00 = (int)((px0 ^ py0) & (HASH_SIZE - 1));
            const int i01 = (int)((px0 ^ py1) & (HASH_SIZE - 1));
            const int i10 = (int)((px1 ^ py0) & (HASH_SIZE - 1));
            const int i11 = (int)((px1 ^ py1) & (HASH_SIZE - 1));
            const float v00 = sCB[off + i00];
            const float v01 = sCB[off + i01];
            const float v10 = sCB[off + i10];
            const float v11 = sCB[off + i11];
            const float vx0 = fmaf(fx, v10 - v00, v00);
            const float vx1 = fmaf(fx, v11 - v01, v01);
            const float feat = fmaf(fy, vx1 - vx0, vx0);
            f32x2 f2; f2.x = feat; f2.y = feat;
#pragma unroll
            for (int j = 0; j < 8; ++j) PKFMA_S(h1[j], f2, wlv[j]);
        };
        dolevel(xy0, h1a);
        dolevel(xy1, h1b);
    }

    auto mlp = [&](f32x2* h1, int n, bool valid) {
        if (!valid) return;
#pragma unroll
        for (int j = 0; j < 8; ++j) {
            h1[j].x = fmaxf(h1[j].x, 0.f);
            h1[j].y = fmaxf(h1[j].y, 0.f);
        }
        float h2[16];
#pragma unroll
        for (int o = 0; o < 16; ++o) {
            const f32x2* w2v = (const f32x2*)(w2b + o * 16);
            f32x2 acc; acc.x = 0.f; acc.y = 0.f;
#pragma unroll
            for (int k = 0; k < 8; ++k) PKFMA_S(acc, h1[k], w2v[k]);
            h2[o] = fmaxf(acc.x + acc.y, 0.f);
        }
        f32x2 h2v[8];
#pragma unroll
        for (int j = 0; j < 8; ++j) { h2v[j].x = h2[2 * j]; h2v[j].y = h2[2 * j + 1]; }
        float rgb[3];
#pragma unroll
        for (int c = 0; c < 3; ++c) {
            const f32x2* w3v = (const f32x2*)(w3b + c * 16);
            f32x2 acc; acc.x = 0.f; acc.y = 0.f;
#pragma unroll
            for (int k = 0; k < 8; ++k) PKFMA_S(acc, h2v[k], w3v[k]);
            rgb[c] = 1.f / (1.f + expf(-(acc.x + acc.y)));
        }
        float* op = out + ((size_t)b * NPTS + n) * 3;
        op[0] = rgb[0]; op[1] = rgb[1]; op[2] = rgb[2];
    };
    mlp(h1a, n0, valid0);
    mlp(h1b, n1, valid1);
}

extern "C" void kernel_launch(void* const* d_in, const int* in_sizes, int n_in,
                              void* d_out, int out_size, void* d_ws, size_t ws_size,
                              hipStream_t stream) {
    const float* x        = (const float*)d_in[0];
    const float* codebook = (const float*)d_in[1];
    const float* w1       = (const float*)d_in[2];
    const float* w2       = (const float*)d_in[3];
    const float* w3       = (const float*)d_in[4];
    float* out = (float*)d_out;

    const int B = in_sizes[0] / (NPTS * 2);

    // host-side ground truth table + hardcode verification
    LevelParams lp;
    bool hard_ok = true;
    int off = 0;
    for (int l = 0; l < NLEV; ++l) {
        const double r = 16.0 * pow(128.0 / 16.0, (double)l / (double)(NLEV - 1));
        const int res = (int)llrint(r);
        if (res != RES_C[l]) hard_ok = false;
        lp.res[l] = res;
        lp.offs[l] = off;
        const int sz = ((long long)(res + 1) * (res + 1) <= HASH_SIZE)
                           ? (res + 1) * (res + 1) : HASH_SIZE;
        off += sz;
    }
    lp.total = off;
    if (off != off_c(NLEV - 1) + size_c(NLEV - 1)) hard_ok = false;

    const size_t w1tBytes = (size_t)B * 16 * NLEV * 4;
    const bool tp = ws_size >= w1tBytes;

    dim3 grid((NPTS + PTS_PER_BLOCK - 1) / PTS_PER_BLOCK, B);

    if (hard_ok && tp) {
        transpose_w1<<<dim3(B), dim3(1024), 0, stream>>>(w1, (float*)d_ws);
        const size_t smemBytes = HBASE + (size_t)NHASH * 4096;   // 155648
        (void)hipFuncSetAttribute((const void*)shacira_hard,
                                  hipFuncAttributeMaxDynamicSharedMemorySize, (int)smemBytes);
        shacira_hard<<<grid, dim3(BLOCK), smemBytes, stream>>>(
            x, codebook, (const float*)d_ws, w2, w3, out);
    } else if (tp) {
        transpose_w1<<<dim3(B), dim3(1024), 0, stream>>>(w1, (float*)d_ws);
        const size_t smemBytes = (size_t)lp.total * 4;
        (void)hipFuncSetAttribute((const void*)shacira_soft<true>,
                                  hipFuncAttributeMaxDynamicSharedMemorySize, (int)smemBytes);
        shacira_soft<true><<<grid, dim3(BLOCK), smemBytes, stream>>>(
            x, codebook, w1, (const float*)d_ws, w2, w3, out, lp);
    } else {
        const size_t smemBytes = (size_t)lp.total * 4;
        (void)hipFuncSetAttribute((const void*)shacira_soft<false>,
                                  hipFuncAttributeMaxDynamicSharedMemorySize, (int)smemBytes);
        shacira_soft<false><<<grid, dim3(BLOCK), smemBytes, stream>>>(
            x, codebook, w1, (const float*)0, w2, w3, out, lp);
    }
}